// Round 9
// baseline (79.816 us; speedup 1.0000x reference)
//
#include <hip/hip_runtime.h>
#include <math.h>

#define BB 8
#define TT 4000
#define AAU 8000
#define PP 8000
#define EE 320000
#define CC 128
#define KT 130
#define KA 37
#define KP 289
#define ROWS 456       // KT+KA+KP
#define NS 70          // slots per batch
#define EBK 64         // edge chunks per batch
#define EPC (EE/EBK)   // 5000 edges per chunk
#define CAPC 12        // per (slot,chunk) entry capacity
#define NWB 115        // weight work-items (4 rows each)
#define ZST 464        // zbuf row stride
#define ST 7           // slots per tile
#define NT 10          // tiles per batch
#define GRID 512
#define CTILE0 (GRID - BB * NT)   // 432: blocks 432..511 own tiles 0..79

// counter slots (stride-16 ints): wdone@0, edone[b]@(1+b), tdone[t]@(9+t), bdone[b]@(89+b)
#define NCTR 97

__device__ __forceinline__ void node_ref(int node, int& t, int& K, int& base, int& row) {
    if (node <= TT)            { t = 0; K = KT; base = 0;        row = node - 1; }
    else if (node <= TT + AAU) { t = 1; K = KA; base = KT;       row = node - TT - 1; }
    else                       { t = 2; K = KP; base = KT + KA;  row = node - TT - AAU - 1; }
}

__device__ __forceinline__ float lrelu02(float v) { return v >= 0.f ? v : 0.2f * v; }
__device__ __forceinline__ unsigned hashid(int id) { return (((unsigned)id * 2654435761u) >> 22) & 511u; }

__device__ __forceinline__ int   ald (const int* p)   { return __hip_atomic_load(p, __ATOMIC_RELAXED, __HIP_MEMORY_SCOPE_AGENT); }
__device__ __forceinline__ float aldf(const float* p) { return __hip_atomic_load(p, __ATOMIC_RELAXED, __HIP_MEMORY_SCOPE_AGENT); }
__device__ __forceinline__ void  asti(int* p, int v)   { __hip_atomic_store(p, v, __ATOMIC_RELAXED, __HIP_MEMORY_SCOPE_AGENT); }
__device__ __forceinline__ void  astf(float* p, float v){ __hip_atomic_store(p, v, __ATOMIC_RELAXED, __HIP_MEMORY_SCOPE_AGENT); }

__device__ __forceinline__ void spin_ge(int* ctr, int target) {
    while (__hip_atomic_load(ctr, __ATOMIC_RELAXED, __HIP_MEMORY_SCOPE_AGENT) < target)
        __builtin_amdgcn_s_sleep(16);
}

template <int K>
__device__ __forceinline__ void loadRow(const float* __restrict__ er, int l, float* v) {
#pragma unroll
    for (int j = 0; j < (K + 63) / 64; ++j) {
        int k = l + 64 * j;
        v[j] = (k < K) ? er[k] : 0.f;
    }
}

template <int K>
__device__ __forceinline__ float dotRegs(const float* v, const float* __restrict__ u, int l) {
    float p = 0.f;
#pragma unroll
    for (int j = 0; j < (K + 63) / 64; ++j) {
        int k = l + 64 * j;
        if (k < K) p += v[j] * u[k];
    }
    return p;
}

template <int K>
__device__ __forceinline__ void accRegs(const float* v, float* __restrict__ z, float w, int l) {
#pragma unroll
    for (int j = 0; j < (K + 63) / 64; ++j) {
        int k = l + 64 * j;
        if (k < K) atomicAdd(&z[k], w * v[j]);
    }
}

// ============ K0: zero the phase counters (replay-safe) ============
__global__ void k0(int* __restrict__ ctr) {
    int i = threadIdx.x;
    for (; i < NCTR * 16; i += 512) ctr[i] = 0;
}

// ============ MEGA: A(weights|dedup|edges) -> B(slot agg) -> C(tile GEMM + MLP) ============
__global__ void __launch_bounds__(512, 4)
mega(const float* __restrict__ temb, const float* __restrict__ aemb, const float* __restrict__ pemb,
     const int* __restrict__ edge_index,
     const int* __restrict__ topic_id, const int* __restrict__ author_id,
     const float* __restrict__ tcnt, const float* __restrict__ acnt,
     const float* __restrict__ Wt, const float* __restrict__ bt,
     const float* __restrict__ Wa, const float* __restrict__ ba,
     const float* __restrict__ Wpw, const float* __restrict__ bpw,
     const float* __restrict__ gatW, const float* __restrict__ attS, const float* __restrict__ attD,
     const float* __restrict__ gatB,
     const float* __restrict__ W1, const float* __restrict__ b1,
     const float* __restrict__ W2, const float* __restrict__ b2,
     const float* __restrict__ W3, const float* __restrict__ b3,
     float* __restrict__ Wp, float* __restrict__ bp,
     float* __restrict__ u_src, float* __restrict__ u_dst, float* __restrict__ c_sd,
     int* __restrict__ slot_node, float* __restrict__ coefT, float* __restrict__ coefA,
     int* __restrict__ a0slot,
     int* __restrict__ cnt2, int* __restrict__ entry_src,
     float* __restrict__ zbuf, float* __restrict__ ppool,
     int* __restrict__ ctr, float* __restrict__ out) {
    __shared__ float SB[7424];          // 29.7 KB, aliased per phase
    __shared__ float redS[8], redD[8];
    __shared__ int s_ret;
    int* SI = (int*)SB;
    int bid = blockIdx.x, tid = threadIdx.x;
    int wv = tid >> 6, l = tid & 63;

    int* wdone = ctr;
    int* edone = ctr + 16;              // [b]*16
    int* tdone = ctr + 9 * 16;          // [t]*16
    int* bdone = ctr + 89 * 16;         // [b]*16

    // ================= PHASE A =================
    if (bid < NWB) {
        // ---- weight item: rows r = bid*4 + (tid>>7); W' = W@gatW; u = W'@att
        int c = tid & 127;
        int r = bid * 4 + (tid >> 7);
        float acc = 0.f;
        const float* wrow = nullptr;
        if (r < KT)             wrow = Wt  + (size_t)r * CC;
        else if (r < KT + KA)   wrow = Wa  + (size_t)(r - KT) * CC;
        else if (r < ROWS)      wrow = Wpw + (size_t)(r - KT - KA) * CC;
        else if (r == ROWS)     wrow = bt;
        else if (r == ROWS + 1) wrow = ba;
        else if (r == ROWS + 2) wrow = bpw;
        if (wrow) {
#pragma unroll 16
            for (int j = 0; j < CC; ++j) acc += wrow[j] * gatW[j * CC + c];
            if (r < ROWS) astf(&Wp[r * CC + c], acc);
            else          astf(&bp[(r - ROWS) * CC + c], acc);
        }
        float ps = acc * attS[c], pd = acc * attD[c];
        for (int o = 32; o; o >>= 1) { ps += __shfl_down(ps, o); pd += __shfl_down(pd, o); }
        if ((tid & 63) == 0) { redS[wv] = ps; redD[wv] = pd; }
        __syncthreads();
        if (tid < 4) {
            int r2 = bid * 4 + tid;
            float us = redS[2 * tid] + redS[2 * tid + 1];
            float ud = redD[2 * tid] + redD[2 * tid + 1];
            if (r2 < ROWS)          { astf(&u_src[r2], us); astf(&u_dst[r2], ud); }
            else if (r2 < ROWS + 3) { astf(&c_sd[r2 - ROWS], us); astf(&c_sd[3 + r2 - ROWS], ud); }
        }
        asm volatile("s_waitcnt vmcnt(0)" ::: "memory");
        __syncthreads();
        if (tid == 0) atomicAdd(wdone, 1);
    } else if (bid < NWB + BB) {
        // ---- dedup item: winner = min position; pooling coefs
        int b = bid - NWB;
        int* hkey = SI;        // 512
        int* hval = SI + 512;  // 512
        int* mt   = SI + 1024; // 70
        int* ma   = SI + 1100; // 70
        for (int i = tid; i < 512; i += 512) { hkey[i] = -1; hval[i] = 0x7fffffff; }
        if (tid < NS) { mt[tid] = 0; ma[tid] = 0; }
        __syncthreads();
        int id = -1, cell = -1;
        if (tid < NS) {
            id = (tid < 50) ? topic_id[b * 50 + tid] : author_id[b * 20 + tid - 50];
            unsigned h = hashid(id);
            while (true) {
                int old = atomicCAS(&hkey[h], -1, id);
                if (old == -1 || old == id) { cell = (int)h; break; }
                h = (h + 1) & 511u;
            }
            atomicMin(&hval[cell], tid);
        }
        __syncthreads();
        int winner = -1;
        if (tid < NS) {
            winner = hval[cell];
            if (tid < 50) atomicAdd(&mt[winner], 1);
            else if (tid > 50) atomicAdd(&ma[winner], 1);
            if (tid == 50) asti(&a0slot[b], winner);
        }
        __syncthreads();
        if (tid < NS) {
            asti(&slot_node[b * NS + tid], (winner == tid) ? id : -1);
            astf(&coefT[b * NS + tid], (float)mt[tid] / (1e-5f + tcnt[b]));
            astf(&coefA[b * NS + tid], (float)ma[tid] / (acnt[b] - 1.00001f));
        }
        asm volatile("s_waitcnt vmcnt(0)" ::: "memory");
        __syncthreads();
        if (tid == 0) atomicAdd(&edone[b * 16], 1);
    }
    __syncthreads();

    // ---- edge item: every block scans chunk = bid
    {
        int b = bid / EBK, chunk = bid % EBK;
        int* hkey = SI;        // 512
        int* hval = SI + 512;  // 512
        int* lcnt = SI + 1024; // 70
        for (int i = tid; i < 512; i += 512) { hkey[i] = -1; hval[i] = 0x7fffffff; }
        if (tid < NS) lcnt[tid] = 0;
        __syncthreads();
        if (tid < NS) {
            int id = (tid < 50) ? topic_id[b * 50 + tid] : author_id[b * 20 + tid - 50];
            unsigned h = hashid(id);
            int cell;
            while (true) {
                int old = atomicCAS(&hkey[h], -1, id);
                if (old == -1 || old == id) { cell = (int)h; break; }
                h = (h + 1) & 511u;
            }
            atomicMin(&hval[cell], tid);
        }
        __syncthreads();
        const int* dsts = edge_index + (size_t)b * 2 * EE + EE + (size_t)chunk * EPC;
        const int* srcs = edge_index + (size_t)b * 2 * EE + (size_t)chunk * EPC;
        for (int e = tid; e < EPC; e += 512) {
            int dst = dsts[e];
            unsigned h = hashid(dst);
            int slot = -1;
            while (true) {
                int k = hkey[h];
                if (k == -1) break;
                if (k == dst) { slot = hval[h]; break; }
                h = (h + 1) & 511u;
            }
            if (slot >= 0) {
                int pos = atomicAdd(&lcnt[slot], 1);
                if (pos < CAPC) asti(&entry_src[((size_t)(b * NS + slot) * EBK + chunk) * CAPC + pos], srcs[e]);
            }
        }
        __syncthreads();
        if (tid < NS) {
            int cn = lcnt[tid]; if (cn > CAPC) cn = CAPC;
            asti(&cnt2[(size_t)(b * NS + tid) * EBK + chunk], cn);
        }
        asm volatile("s_waitcnt vmcnt(0)" ::: "memory");
        __syncthreads();
        if (tid == 0) atomicAdd(&edone[b * 16], 1);
    }
    __syncthreads();

    // ================= PHASE B: slot aggregation =================
    {
        float* u_l   = SB;          // 456
        float* ud_l  = SB + 456;    // 456
        float* z_l   = SB + 912;    // 456
        float* csd_l = SB + 1368;   // 6
        float* misc  = SB + 1376;   // 4
        int* counts_l = SI + 1380;  // 64
        int* eid_l    = SI + 1444;  // 768

        for (int item = bid; item < BB * NS; item += GRID) {
            int b = item / NS, s = item - b * NS;
            int tile = b * NT + s / ST;
            if (tid == 0) {
                spin_ge(wdone, NWB);
                spin_ge(&edone[b * 16], EBK + 1);
            }
            __syncthreads();
            int node = ald(&slot_node[item]);
            if (node >= 0) {
                for (int i = tid; i < ROWS; i += 512) {
                    u_l[i] = aldf(&u_src[i]); ud_l[i] = aldf(&u_dst[i]); z_l[i] = 0.f;
                }
                if (tid < EBK) counts_l[tid] = ald(&cnt2[(size_t)item * EBK + tid]);
                if (tid < 6) csd_l[tid] = aldf(&c_sd[tid]);
                if (tid < 4) misc[tid] = 0.f;
                for (int i = tid; i < EBK * CAPC; i += 512)
                    eid_l[i] = ald(&entry_src[(size_t)item * EBK * CAPC + i]);
                __syncthreads();

                const float* tb = temb + (size_t)b * TT * KT;
                const float* ab = aemb + (size_t)b * AAU * KA;
                const float* pb = pemb + (size_t)b * PP * KP;
                float v[5];
                float adraw;
                {   // self (all waves compute; wave 0 accumulates)
                    int t, K, base, row; node_ref(node, t, K, base, row);
                    float ps = 0.f, pd = 0.f;
                    if (t == 0)      { const float* er = tb + (size_t)row * KT; loadRow<KT>(er, l, v); ps = dotRegs<KT>(v, u_l, l);           pd = dotRegs<KT>(v, ud_l, l); }
                    else if (t == 1) { const float* er = ab + (size_t)row * KA; loadRow<KA>(er, l, v); ps = dotRegs<KA>(v, u_l + KT, l);      pd = dotRegs<KA>(v, ud_l + KT, l); }
                    else             { const float* er = pb + (size_t)row * KP; loadRow<KP>(er, l, v); ps = dotRegs<KP>(v, u_l + KT + KA, l); pd = dotRegs<KP>(v, ud_l + KT + KA, l); }
                    for (int o = 32; o; o >>= 1) { ps += __shfl_xor(ps, o); pd += __shfl_xor(pd, o); }
                    float asrc = ps + csd_l[t];
                    adraw = pd + csd_l[3 + t];
                    float wself = expf(lrelu02(asrc + adraw));
                    if (wv == 0) {
                        if (t == 0)      accRegs<KT>(v, z_l, wself, l);
                        else if (t == 1) accRegs<KA>(v, z_l + KT, wself, l);
                        else             accRegs<KP>(v, z_l + KT + KA, wself, l);
                        if (l == 0) { atomicAdd(&misc[0], wself); atomicAdd(&misc[1 + t], wself); }
                    }
                }
                for (int chunk = wv; chunk < EBK; chunk += 8) {
                    int cn = counts_l[chunk];
                    for (int j = 0; j < cn; ++j) {
                        int src = eid_l[chunk * CAPC + j];
                        int t, K, base, row; node_ref(src, t, K, base, row);
                        float p = 0.f;
                        if (t == 0)      { const float* er = tb + (size_t)row * KT; loadRow<KT>(er, l, v); p = dotRegs<KT>(v, u_l, l); }
                        else if (t == 1) { const float* er = ab + (size_t)row * KA; loadRow<KA>(er, l, v); p = dotRegs<KA>(v, u_l + KT, l); }
                        else             { const float* er = pb + (size_t)row * KP; loadRow<KP>(er, l, v); p = dotRegs<KP>(v, u_l + KT + KA, l); }
                        for (int o = 32; o; o >>= 1) p += __shfl_xor(p, o);
                        float w = expf(lrelu02(p + csd_l[t] + adraw));
                        if (t == 0)      accRegs<KT>(v, z_l, w, l);
                        else if (t == 1) accRegs<KA>(v, z_l + KT, w, l);
                        else             accRegs<KP>(v, z_l + KT + KA, w, l);
                        if (l == 0) { atomicAdd(&misc[0], w); atomicAdd(&misc[1 + t], w); }
                    }
                }
                __syncthreads();
                float* zo = zbuf + (size_t)item * ZST;
                for (int i = tid; i < ROWS; i += 512) astf(&zo[i], z_l[i]);
                if (tid >= ROWS && tid < ROWS + 3) astf(&zo[tid], misc[tid - ROWS + 1]);
                if (tid == ROWS + 3) astf(&zo[tid], misc[0] + 1e-16f);
                asm volatile("s_waitcnt vmcnt(0)" ::: "memory");
            }
            __syncthreads();
            if (tid == 0) atomicAdd(&tdone[tile * 16], 1);
            __syncthreads();
        }
    }

    // ================= PHASE C: tile GEMM + pooling + MLP finisher =================
    if (bid >= CTILE0) {
        int ct = bid - CTILE0;          // tile 0..79
        int b = ct / NT, tt = ct % NT;
        int s0 = tt * ST, bN = b * NS;
        float* Z     = SB;              // 7*456 = 3192
        float* red   = SB + 3192;       // 4*7*128 = 3584
        float* tpool = SB + 6776;       // 384
        float* swd   = SB + 7160;       // 28
        int*   nodes = SI + 7188;       // 7

        if (tid == 0) spin_ge(&tdone[ct * 16], ST);
        __syncthreads();

        if (tid < ST) {
            nodes[tid] = ald(&slot_node[bN + s0 + tid]);
            const float* zt = zbuf + (size_t)(bN + s0 + tid) * ZST + ROWS;
            swd[tid * 4 + 0] = aldf(&zt[0]); swd[tid * 4 + 1] = aldf(&zt[1]);
            swd[tid * 4 + 2] = aldf(&zt[2]); swd[tid * 4 + 3] = aldf(&zt[3]);
        }
        if (tid < 384) tpool[tid] = 0.f;
        __syncthreads();
        for (int i = tid; i < ST * ROWS; i += 512) {
            int s = i / ROWS, k = i - s * ROWS;
            Z[i] = (nodes[s] >= 0) ? aldf(&zbuf[(size_t)(bN + s0 + s) * ZST + k]) : 0.f;
        }
        __syncthreads();

        // GEMM: k-group g owns k-slice (112/112/112/120), pipelined Wp loads
        int g = tid >> 7, c = tid & 127;
        const int k0i = g * 112;
        const int klen = (g == 3) ? 120 : 112;
        float acc[ST];
#pragma unroll
        for (int s = 0; s < ST; ++s) acc[s] = 0.f;
        {
            float w[8], wn[8];
            const float* wpc = Wp + c;
#pragma unroll
            for (int u = 0; u < 8; ++u) w[u] = aldf(&wpc[(k0i + u) * CC]);
            for (int kk = 0; kk < klen; kk += 8) {
                int kn = kk + 8;
                if (kn < klen) {
#pragma unroll
                    for (int u = 0; u < 8; ++u) wn[u] = aldf(&wpc[(k0i + kn + u) * CC]);
                }
#pragma unroll
                for (int s = 0; s < ST; ++s) {
                    const float4 za = *(const float4*)&Z[s * ROWS + k0i + kk];
                    const float4 zb = *(const float4*)&Z[s * ROWS + k0i + kk + 4];
                    acc[s] += za.x * w[0] + za.y * w[1] + za.z * w[2] + za.w * w[3]
                            + zb.x * w[4] + zb.y * w[5] + zb.z * w[6] + zb.w * w[7];
                }
#pragma unroll
                for (int u = 0; u < 8; ++u) w[u] = wn[u];
            }
        }
#pragma unroll
        for (int s = 0; s < ST; ++s) red[(g * ST + s) * CC + c] = acc[s];
        __syncthreads();

        {   // finalize h + pooled partials
            int a0s = ald(&a0slot[b]);
            for (int i = tid; i < ST * CC; i += 512) {
                int s = i >> 7, cc2 = i & 127;
                if (nodes[s] < 0) continue;
                float hsum = red[s * CC + cc2] + red[(ST + s) * CC + cc2]
                           + red[(2 * ST + s) * CC + cc2] + red[(3 * ST + s) * CC + cc2];
                float sw0 = swd[s * 4], sw1 = swd[s * 4 + 1], sw2 = swd[s * 4 + 2], den = swd[s * 4 + 3];
                float hv = (hsum + sw0 * aldf(&bp[cc2]) + sw1 * aldf(&bp[CC + cc2])
                                 + sw2 * aldf(&bp[2 * CC + cc2])) / den + gatB[cc2];
                hv = fmaxf(hv, 0.f);
                int gs = s0 + s;
                if (gs == a0s) tpool[cc2] = hv;
                float cA = aldf(&coefA[bN + gs]);
                if (cA != 0.f) atomicAdd(&tpool[128 + cc2], cA * hv);
                float cT = aldf(&coefT[bN + gs]);
                if (cT != 0.f) atomicAdd(&tpool[256 + cc2], cT * hv);
            }
        }
        __syncthreads();
        if (tid < 384) astf(&ppool[((size_t)b * NT + tt) * 384 + tid], tpool[tid]);
        asm volatile("s_waitcnt vmcnt(0)" ::: "memory");
        __syncthreads();
        if (tid == 0) s_ret = atomicAdd(&bdone[b * 16], 1);
        __syncthreads();

        if (s_ret == NT - 1) {
            float* catL = red;            // 384
            float* h1   = red + 384;      // 256
            float* h2   = red + 640;      // 128
            float* rA   = red + 768;      // 512
            float* rB   = red + 1280;     // 512
            if (tid < 384) {
                float sm = 0.f;
#pragma unroll
                for (int t = 0; t < NT; ++t)
                    sm += aldf(&ppool[((size_t)b * NT + t) * 384 + tid]);
                catL[tid] = sm;
            }
            __syncthreads();
            {
                int cl = tid & 255, half = tid >> 8;
                const int kb = half * 192, ke = kb + 192;
                float a1 = 0.f;
#pragma unroll 8
                for (int k = kb; k < ke; ++k) a1 += catL[k] * W1[k * 256 + cl];
                rA[half * 256 + cl] = a1;
            }
            __syncthreads();
            if (tid < 256) h1[tid] = tanhf(b1[tid] + rA[tid] + rA[256 + tid]);
            __syncthreads();
            {
                int cl = tid & 127, q = tid >> 7;
                const int kb = q * 64, ke = kb + 64;
                float a2 = 0.f;
#pragma unroll 8
                for (int k = kb; k < ke; ++k) a2 += h1[k] * W2[k * CC + cl];
                rB[q * CC + cl] = a2;
            }
            __syncthreads();
            if (tid < 128) {
                float vv = tanhf(b2[tid] + rB[tid] + rB[CC + tid] + rB[2 * CC + tid] + rB[3 * CC + tid]);
                h2[tid] = vv * W3[tid];
            }
            __syncthreads();
            if (tid < 64) {
                float sm = h2[tid] + h2[tid + 64];
                for (int o = 32; o; o >>= 1) sm += __shfl_down(sm, o);
                if (tid == 0) out[b] = sm + b3[0];
            }
        }
    }
}

extern "C" void kernel_launch(void* const* d_in, const int* in_sizes, int n_in,
                              void* d_out, int out_size, void* d_ws, size_t ws_size,
                              hipStream_t stream) {
    const float* temb = (const float*)d_in[0];
    const float* aemb = (const float*)d_in[1];
    const float* pemb = (const float*)d_in[2];
    // d_in[3..5] = topic_set/author_set/paper_set: deterministic aranges - folded analytically
    const int* edge_index = (const int*)d_in[6];
    const int* topic_id   = (const int*)d_in[7];
    const int* author_id  = (const int*)d_in[8];
    const float* tcnt = (const float*)d_in[9];
    const float* acnt = (const float*)d_in[10];
    const float* Wt  = (const float*)d_in[11];
    const float* bt  = (const float*)d_in[12];
    const float* Wa  = (const float*)d_in[13];
    const float* ba  = (const float*)d_in[14];
    const float* Wpw = (const float*)d_in[15];
    const float* bpw = (const float*)d_in[16];
    const float* gatW = (const float*)d_in[17];
    const float* attS = (const float*)d_in[18];
    const float* attD = (const float*)d_in[19];
    const float* gatB = (const float*)d_in[20];
    const float* W1 = (const float*)d_in[21];
    const float* b1 = (const float*)d_in[22];
    const float* W2 = (const float*)d_in[23];
    const float* b2 = (const float*)d_in[24];
    const float* W3 = (const float*)d_in[25];
    const float* b3 = (const float*)d_in[26];

    char* ws = (char*)d_ws;
    size_t off = 0;
    auto alloc = [&](size_t bytes) -> void* {
        void* p = ws + off;
        off = (off + bytes + 255) & ~(size_t)255;
        return p;
    };
    float* Wp      = (float*)alloc((size_t)ROWS * CC * 4);
    float* bp      = (float*)alloc(3 * CC * 4);
    float* u_src   = (float*)alloc(ROWS * 4);
    float* u_dst   = (float*)alloc(ROWS * 4);
    float* c_sd    = (float*)alloc(6 * 4);
    int* slot_node = (int*)alloc(BB * NS * 4);
    float* coefT   = (float*)alloc(BB * NS * 4);
    float* coefA   = (float*)alloc(BB * NS * 4);
    int* a0slot    = (int*)alloc(BB * 4);
    int* cnt2      = (int*)alloc((size_t)BB * NS * EBK * 4);
    int* entry_src = (int*)alloc((size_t)BB * NS * EBK * CAPC * 4);
    float* zbuf    = (float*)alloc((size_t)BB * NS * ZST * 4);
    float* ppool   = (float*)alloc((size_t)BB * NT * 384 * 4);
    int* ctr       = (int*)alloc(NCTR * 16 * 4);
    (void)ws_size; (void)in_sizes; (void)n_in; (void)out_size;

    k0<<<dim3(1), dim3(512), 0, stream>>>(ctr);
    mega<<<dim3(GRID), dim3(512), 0, stream>>>(
        temb, aemb, pemb, edge_index, topic_id, author_id, tcnt, acnt,
        Wt, bt, Wa, ba, Wpw, bpw, gatW, attS, attD, gatB,
        W1, b1, W2, b2, W3, b3,
        Wp, bp, u_src, u_dst, c_sd,
        slot_node, coefT, coefA, a0slot,
        cnt2, entry_src, zbuf, ppool, ctr, (float*)d_out);
}

// Round 11
// 66.622 us; speedup vs baseline: 1.1981x; 1.1981x over previous
//
#include <hip/hip_runtime.h>
#include <math.h>

#define BB 8
#define TT 4000
#define AAU 8000
#define PP 8000
#define EE 320000
#define CC 128
#define KT 130
#define KA 37
#define KP 289
#define ROWS 456       // KT+KA+KP
#define NS 70          // slots per batch
#define EBK 64         // edge chunks per batch
#define EPC (EE/EBK)   // 5000 edges per chunk
#define CAPC 12        // per (slot,chunk) entry capacity
#define NWB 115        // weight blocks (4 rows each)
#define ZST 464        // zbuf row stride (456 z + sw0,sw1,sw2,den_raw + pad)
#define NSUB 4         // agg sub-blocks per slot (16 chunks each)
#define ST 7           // slots per k3 tile
#define NT 10          // tiles per batch

__device__ __forceinline__ void node_ref(int node, int& t, int& K, int& base, int& row) {
    if (node <= TT)            { t = 0; K = KT; base = 0;        row = node - 1; }
    else if (node <= TT + AAU) { t = 1; K = KA; base = KT;       row = node - TT - 1; }
    else                       { t = 2; K = KP; base = KT + KA;  row = node - TT - AAU - 1; }
}

__device__ __forceinline__ float lrelu02(float v) { return v >= 0.f ? v : 0.2f * v; }
__device__ __forceinline__ unsigned hashid(int id) { return (((unsigned)id * 2654435761u) >> 22) & 511u; }

template <int K>
__device__ __forceinline__ void loadRow(const float* __restrict__ er, int l, float* v) {
#pragma unroll
    for (int j = 0; j < (K + 63) / 64; ++j) {
        int k = l + 64 * j;
        v[j] = (k < K) ? er[k] : 0.f;
    }
}

template <int K>
__device__ __forceinline__ float dotRegs(const float* v, const float* __restrict__ u, int l) {
    float p = 0.f;
#pragma unroll
    for (int j = 0; j < (K + 63) / 64; ++j) {
        int k = l + 64 * j;
        if (k < K) p += v[j] * u[k];
    }
    return p;
}

template <int K>
__device__ __forceinline__ void accRegs(const float* v, float* __restrict__ z, float w, int l) {
#pragma unroll
    for (int j = 0; j < (K + 63) / 64; ++j) {
        int k = l + 64 * j;
        if (k < K) atomicAdd(&z[k], w * v[j]);
    }
}

// ============ K1: weights (0..114) | dedup+coef (115..122) | edge scan (123..634) ============
__global__ void __launch_bounds__(512)
k1(const float* __restrict__ Wt, const float* __restrict__ Wa, const float* __restrict__ Wpp,
   const float* __restrict__ bt, const float* __restrict__ ba, const float* __restrict__ bpw,
   const float* __restrict__ gatW, const float* __restrict__ attS, const float* __restrict__ attD,
   const int* __restrict__ topic_id, const int* __restrict__ author_id,
   const int* __restrict__ edge_index,
   const float* __restrict__ tcnt, const float* __restrict__ acnt,
   float* __restrict__ Wp, float* __restrict__ bp,
   float* __restrict__ u_src, float* __restrict__ u_dst, float* __restrict__ c_sd,
   int* __restrict__ slot_node, float* __restrict__ coefT, float* __restrict__ coefA,
   int* __restrict__ a0slot,
   int* __restrict__ cnt2, int* __restrict__ entry_src, int* __restrict__ done) {
    __shared__ int hkey[512], hval[512], lcnt[NS], mt[NS], ma[NS];
    __shared__ float redS[8], redD[8];
    int bid = blockIdx.x, tid = threadIdx.x;

    if (bid < NWB) {
        int c = tid & 127;
        int r = bid * 4 + (tid >> 7);
        float acc = 0.f;
        const float* wrow = nullptr;
        if (r < KT)             wrow = Wt  + (size_t)r * CC;
        else if (r < KT + KA)   wrow = Wa  + (size_t)(r - KT) * CC;
        else if (r < ROWS)      wrow = Wpp + (size_t)(r - KT - KA) * CC;
        else if (r == ROWS)     wrow = bt;
        else if (r == ROWS + 1) wrow = ba;
        else if (r == ROWS + 2) wrow = bpw;
        if (wrow) {
#pragma unroll 16
            for (int j = 0; j < CC; ++j) acc += wrow[j] * gatW[j * CC + c];
            if (r < ROWS) Wp[r * CC + c] = acc;
            else          bp[(r - ROWS) * CC + c] = acc;
        }
        float ps = acc * attS[c], pd = acc * attD[c];
        for (int o = 32; o; o >>= 1) { ps += __shfl_down(ps, o); pd += __shfl_down(pd, o); }
        int w = tid >> 6;
        if ((tid & 63) == 0) { redS[w] = ps; redD[w] = pd; }
        __syncthreads();
        if (tid < 4) {
            int r2 = bid * 4 + tid;
            float us = redS[2 * tid] + redS[2 * tid + 1];
            float ud = redD[2 * tid] + redD[2 * tid + 1];
            if (r2 < ROWS)          { u_src[r2] = us; u_dst[r2] = ud; }
            else if (r2 < ROWS + 3) { c_sd[r2 - ROWS] = us; c_sd[3 + r2 - ROWS] = ud; }
        }
    } else if (bid < NWB + BB) {
        int b = bid - NWB;
        for (int i = tid; i < 512; i += 512) { hkey[i] = -1; hval[i] = 0x7fffffff; }
        if (tid < NS) { mt[tid] = 0; ma[tid] = 0; }
        if (tid == 0) done[b * 16] = 0;
        __syncthreads();
        int id = -1, cell = -1;
        if (tid < NS) {
            id = (tid < 50) ? topic_id[b * 50 + tid] : author_id[b * 20 + tid - 50];
            unsigned h = hashid(id);
            while (true) {
                int old = atomicCAS(&hkey[h], -1, id);
                if (old == -1 || old == id) { cell = (int)h; break; }
                h = (h + 1) & 511u;
            }
            atomicMin(&hval[cell], tid);
        }
        __syncthreads();
        int winner = -1;
        if (tid < NS) {
            winner = hval[cell];
            if (tid < 50) atomicAdd(&mt[winner], 1);
            else if (tid > 50) atomicAdd(&ma[winner], 1);
            if (tid == 50) a0slot[b] = winner;
        }
        __syncthreads();
        if (tid < NS) {
            slot_node[b * NS + tid] = (winner == tid) ? id : -1;
            coefT[b * NS + tid] = (float)mt[tid] / (1e-5f + tcnt[b]);
            coefA[b * NS + tid] = (float)ma[tid] / (acnt[b] - 1.00001f);
        }
    } else {
        int eb = bid - NWB - BB;
        int b = eb / EBK, chunk = eb % EBK;
        for (int i = tid; i < 512; i += 512) { hkey[i] = -1; hval[i] = 0x7fffffff; }
        if (tid < NS) lcnt[tid] = 0;
        __syncthreads();
        if (tid < NS) {
            int id = (tid < 50) ? topic_id[b * 50 + tid] : author_id[b * 20 + tid - 50];
            unsigned h = hashid(id);
            int cell;
            while (true) {
                int old = atomicCAS(&hkey[h], -1, id);
                if (old == -1 || old == id) { cell = (int)h; break; }
                h = (h + 1) & 511u;
            }
            atomicMin(&hval[cell], tid);
        }
        __syncthreads();
        const int* dsts = edge_index + (size_t)b * 2 * EE + EE + (size_t)chunk * EPC;
        const int* srcs = edge_index + (size_t)b * 2 * EE + (size_t)chunk * EPC;
        for (int e = tid; e < EPC; e += 512) {
            int dst = dsts[e];
            unsigned h = hashid(dst);
            int slot = -1;
            while (true) {
                int k = hkey[h];
                if (k == -1) break;
                if (k == dst) { slot = hval[h]; break; }
                h = (h + 1) & 511u;
            }
            if (slot >= 0) {
                int pos = atomicAdd(&lcnt[slot], 1);
                if (pos < CAPC) entry_src[((size_t)(b * NS + slot) * EBK + chunk) * CAPC + pos] = srcs[e];
            }
        }
        __syncthreads();
        if (tid < NS) {
            int cn = lcnt[tid]; if (cn > CAPC) cn = CAPC;
            cnt2[(size_t)(b * NS + tid) * EBK + chunk] = cn;
        }
    }
}

// ============ K2: agg, NSUB=4 independent sub-blocks per slot (16 chunks each) ============
__global__ void __launch_bounds__(256)
k2(const float* __restrict__ temb, const float* __restrict__ aemb, const float* __restrict__ pemb,
   const int* __restrict__ slot_node, const int* __restrict__ cnt2, const int* __restrict__ entry_src,
   const float* __restrict__ u_src, const float* __restrict__ u_dst, const float* __restrict__ c_sd,
   float* __restrict__ zbuf4) {
    __shared__ float u_l[ROWS], ud_l[ROWS], z_l[ROWS];
    __shared__ int counts_l[16];
    __shared__ float csd_l[6], misc[4];   // denom_raw, sw0, sw1, sw2
    int bid = blockIdx.x;
    int item = bid >> 2, q = bid & 3;     // slot item, sub-block
    int b = item / NS;
    int node = slot_node[item];
    if (node < 0) return;
    int tid = threadIdx.x, wv = tid >> 6, l = tid & 63;

    for (int i = tid; i < ROWS; i += 256) { u_l[i] = u_src[i]; ud_l[i] = u_dst[i]; z_l[i] = 0.f; }
    if (tid < 16) counts_l[tid] = cnt2[(size_t)item * EBK + q * 16 + tid];
    if (tid < 6) csd_l[tid] = c_sd[tid];
    if (tid < 4) misc[tid] = 0.f;
    __syncthreads();

    const float* tb = temb + (size_t)b * TT * KT;
    const float* ab = aemb + (size_t)b * AAU * KA;
    const float* pb = pemb + (size_t)b * PP * KP;
    float v[5];
    float adraw;
    {   // self dot: every wave computes (adraw needed by all); only q==0/wv==0 accumulates
        int t, K, base, row; node_ref(node, t, K, base, row);
        float ps = 0.f, pd = 0.f;
        if (t == 0)      { const float* er = tb + (size_t)row * KT; loadRow<KT>(er, l, v); ps = dotRegs<KT>(v, u_l, l);           pd = dotRegs<KT>(v, ud_l, l); }
        else if (t == 1) { const float* er = ab + (size_t)row * KA; loadRow<KA>(er, l, v); ps = dotRegs<KA>(v, u_l + KT, l);      pd = dotRegs<KA>(v, ud_l + KT, l); }
        else             { const float* er = pb + (size_t)row * KP; loadRow<KP>(er, l, v); ps = dotRegs<KP>(v, u_l + KT + KA, l); pd = dotRegs<KP>(v, ud_l + KT + KA, l); }
        for (int o = 32; o; o >>= 1) { ps += __shfl_xor(ps, o); pd += __shfl_xor(pd, o); }
        float asrc = ps + csd_l[t];
        adraw = pd + csd_l[3 + t];
        if (q == 0 && wv == 0) {
            float wself = expf(lrelu02(asrc + adraw));
            if (t == 0)      accRegs<KT>(v, z_l, wself, l);
            else if (t == 1) accRegs<KA>(v, z_l + KT, wself, l);
            else             accRegs<KP>(v, z_l + KT + KA, wself, l);
            if (l == 0) { atomicAdd(&misc[0], wself); atomicAdd(&misc[1 + t], wself); }
        }
    }
    // this sub-block's 16 chunks: wave wv handles 4 (wv, wv+4, wv+8, wv+12)
    for (int ci = wv; ci < 16; ci += 4) {
        int cn = counts_l[ci];
        const int* ep = entry_src + ((size_t)item * EBK + q * 16 + ci) * CAPC;
        for (int j = 0; j < cn; ++j) {
            int src = ep[j];
            int t, K, base, row; node_ref(src, t, K, base, row);
            float p = 0.f;
            if (t == 0)      { const float* er = tb + (size_t)row * KT; loadRow<KT>(er, l, v); p = dotRegs<KT>(v, u_l, l); }
            else if (t == 1) { const float* er = ab + (size_t)row * KA; loadRow<KA>(er, l, v); p = dotRegs<KA>(v, u_l + KT, l); }
            else             { const float* er = pb + (size_t)row * KP; loadRow<KP>(er, l, v); p = dotRegs<KP>(v, u_l + KT + KA, l); }
            for (int o = 32; o; o >>= 1) p += __shfl_xor(p, o);
            float w = expf(lrelu02(p + csd_l[t] + adraw));
            if (t == 0)      accRegs<KT>(v, z_l, w, l);
            else if (t == 1) accRegs<KA>(v, z_l + KT, w, l);
            else             accRegs<KP>(v, z_l + KT + KA, w, l);
            if (l == 0) { atomicAdd(&misc[0], w); atomicAdd(&misc[1 + t], w); }
        }
    }
    __syncthreads();

    // write partial z + tails (256-thread block: tail writers are tid 0..3)
    float* zo = zbuf4 + (size_t)bid * ZST;   // bid = item*4 + q
    for (int i = tid; i < ROWS; i += 256) zo[i] = z_l[i];
    if (tid < 3)  zo[ROWS + tid] = misc[1 + tid];   // sw0, sw1, sw2
    if (tid == 3) zo[ROWS + 3]   = misc[0];         // denom_raw
}

// ============ K3: 7-slot tile GEMM (pipelined Wp loads, 4-partial Z sum) + pool + MLP finisher ============
__global__ void __launch_bounds__(512)
k3(const float* __restrict__ zbuf4, const int* __restrict__ slot_node,
   const float* __restrict__ coefT, const float* __restrict__ coefA,
   const int* __restrict__ a0slot,
   const float* __restrict__ Wp, const float* __restrict__ bp, const float* __restrict__ gatB,
   const float* __restrict__ W1, const float* __restrict__ b1,
   const float* __restrict__ W2, const float* __restrict__ b2,
   const float* __restrict__ W3, const float* __restrict__ b3,
   float* __restrict__ ppool, int* __restrict__ done, float* __restrict__ out) {
    __shared__ float Z[ST * ROWS];        // 12.8 KB
    __shared__ float red[4 * ST * CC];    // 14.3 KB (reused by finisher MLP)
    __shared__ float tpool[384];
    __shared__ float swd[ST * 4];
    __shared__ int nodes[ST];
    __shared__ int s_ret;
    int blk = blockIdx.x, b = blk / NT, tile = blk % NT;
    int tid = threadIdx.x;
    int g = tid >> 7, c = tid & 127;
    int s0 = tile * ST, bN = b * NS;

    if (tid < ST) {
        nodes[tid] = slot_node[bN + s0 + tid];
        float sw0 = 0.f, sw1 = 0.f, sw2 = 0.f, dr = 0.f;
        if (nodes[tid] >= 0) {
#pragma unroll
            for (int qq = 0; qq < NSUB; ++qq) {
                const float* zt = zbuf4 + (size_t)((bN + s0 + tid) * NSUB + qq) * ZST + ROWS;
                sw0 += zt[0]; sw1 += zt[1]; sw2 += zt[2]; dr += zt[3];
            }
        }
        swd[tid * 4 + 0] = sw0; swd[tid * 4 + 1] = sw1;
        swd[tid * 4 + 2] = sw2; swd[tid * 4 + 3] = dr + 1e-16f;
    }
    if (tid < 384) tpool[tid] = 0.f;
    __syncthreads();
    for (int i = tid; i < ST * ROWS; i += 512) {
        int s = i / ROWS, k = i - s * ROWS;
        float zv = 0.f;
        if (nodes[s] >= 0) {
            const float* zr = zbuf4 + (size_t)((bN + s0 + s) * NSUB) * ZST + k;
            zv = zr[0] + zr[ZST] + zr[2 * ZST] + zr[3 * ZST];
        }
        Z[i] = zv;
    }
    __syncthreads();

    // GEMM: k-group g owns k-slice (112/112/112/120), pipelined Wp loads
    const int k0i = g * 112;
    const int klen = (g == 3) ? 120 : 112;
    float acc[ST];
#pragma unroll
    for (int s = 0; s < ST; ++s) acc[s] = 0.f;
    {
        float w[8], wn[8];
        const float* wpc = Wp + c;
#pragma unroll
        for (int u = 0; u < 8; ++u) w[u] = wpc[(k0i + u) * CC];
        for (int kk = 0; kk < klen; kk += 8) {
            int kn = kk + 8;
            if (kn < klen) {
#pragma unroll
                for (int u = 0; u < 8; ++u) wn[u] = wpc[(k0i + kn + u) * CC];
            }
#pragma unroll
            for (int s = 0; s < ST; ++s) {
                const float4 za = *(const float4*)&Z[s * ROWS + k0i + kk];
                const float4 zb = *(const float4*)&Z[s * ROWS + k0i + kk + 4];
                acc[s] += za.x * w[0] + za.y * w[1] + za.z * w[2] + za.w * w[3]
                        + zb.x * w[4] + zb.y * w[5] + zb.z * w[6] + zb.w * w[7];
            }
#pragma unroll
            for (int u = 0; u < 8; ++u) w[u] = wn[u];
        }
    }
#pragma unroll
    for (int s = 0; s < ST; ++s) red[(g * ST + s) * CC + c] = acc[s];
    __syncthreads();

    {   // finalize h per slot + pooled partials
        int a0s = a0slot[b];
        for (int i = tid; i < ST * CC; i += 512) {
            int s = i >> 7, cc2 = i & 127;
            if (nodes[s] < 0) continue;
            float hsum = red[s * CC + cc2] + red[(ST + s) * CC + cc2]
                       + red[(2 * ST + s) * CC + cc2] + red[(3 * ST + s) * CC + cc2];
            float sw0 = swd[s * 4], sw1 = swd[s * 4 + 1], sw2 = swd[s * 4 + 2], den = swd[s * 4 + 3];
            float hv = (hsum + sw0 * bp[cc2] + sw1 * bp[CC + cc2] + sw2 * bp[2 * CC + cc2]) / den + gatB[cc2];
            hv = fmaxf(hv, 0.f);
            int gs = s0 + s;
            if (gs == a0s) tpool[cc2] = hv;   // unique writer
            float cA = coefA[bN + gs];
            if (cA != 0.f) atomicAdd(&tpool[128 + cc2], cA * hv);
            float cT = coefT[bN + gs];
            if (cT != 0.f) atomicAdd(&tpool[256 + cc2], cT * hv);
        }
    }
    __syncthreads();
    if (tid < 384) {
        __hip_atomic_store(&ppool[((size_t)b * NT + tile) * 384 + tid], tpool[tid],
                           __ATOMIC_RELAXED, __HIP_MEMORY_SCOPE_AGENT);
    }
    asm volatile("s_waitcnt vmcnt(0)" ::: "memory");
    __syncthreads();
    if (tid == 0) s_ret = atomicAdd(&done[b * 16], 1);
    __syncthreads();

    if (s_ret == NT - 1) {
        float* catL = red;            // 384
        float* h1   = red + 384;      // 256
        float* h2   = red + 640;      // 128
        float* rA   = red + 768;      // 512
        float* rB   = red + 1280;     // 512
        if (tid < 384) {
            float s = 0.f;
#pragma unroll
            for (int t = 0; t < NT; ++t)
                s += __hip_atomic_load(&ppool[((size_t)b * NT + t) * 384 + tid],
                                       __ATOMIC_RELAXED, __HIP_MEMORY_SCOPE_AGENT);
            catL[tid] = s;
        }
        __syncthreads();
        {   // layer 1: 384x256, k split 2-way
            int cl = tid & 255, half = tid >> 8;
            const int kb = half * 192, ke = kb + 192;
            float acc1 = 0.f;
#pragma unroll 8
            for (int k = kb; k < ke; ++k) acc1 += catL[k] * W1[k * 256 + cl];
            rA[half * 256 + cl] = acc1;
        }
        __syncthreads();
        if (tid < 256) h1[tid] = tanhf(b1[tid] + rA[tid] + rA[256 + tid]);
        __syncthreads();
        {   // layer 2: 256x128, k split 4-way
            int cl = tid & 127, qd = tid >> 7;
            const int kb = qd * 64, ke = kb + 64;
            float acc2 = 0.f;
#pragma unroll 8
            for (int k = kb; k < ke; ++k) acc2 += h1[k] * W2[k * CC + cl];
            rB[qd * CC + cl] = acc2;
        }
        __syncthreads();
        if (tid < 128) {
            float vv = tanhf(b2[tid] + rB[tid] + rB[CC + tid] + rB[2 * CC + tid] + rB[3 * CC + tid]);
            h2[tid] = vv * W3[tid];
        }
        __syncthreads();
        if (tid < 64) {
            float sm = h2[tid] + h2[tid + 64];
            for (int o = 32; o; o >>= 1) sm += __shfl_down(sm, o);
            if (tid == 0) out[b] = sm + b3[0];
        }
    }
}

extern "C" void kernel_launch(void* const* d_in, const int* in_sizes, int n_in,
                              void* d_out, int out_size, void* d_ws, size_t ws_size,
                              hipStream_t stream) {
    const float* temb = (const float*)d_in[0];
    const float* aemb = (const float*)d_in[1];
    const float* pemb = (const float*)d_in[2];
    // d_in[3..5] = topic_set/author_set/paper_set: deterministic aranges - folded analytically
    const int* edge_index = (const int*)d_in[6];
    const int* topic_id   = (const int*)d_in[7];
    const int* author_id  = (const int*)d_in[8];
    const float* tcnt = (const float*)d_in[9];
    const float* acnt = (const float*)d_in[10];
    const float* Wt  = (const float*)d_in[11];
    const float* bt  = (const float*)d_in[12];
    const float* Wa  = (const float*)d_in[13];
    const float* ba  = (const float*)d_in[14];
    const float* Wpw = (const float*)d_in[15];
    const float* bpw = (const float*)d_in[16];
    const float* gatW = (const float*)d_in[17];
    const float* attS = (const float*)d_in[18];
    const float* attD = (const float*)d_in[19];
    const float* gatB = (const float*)d_in[20];
    const float* W1 = (const float*)d_in[21];
    const float* b1 = (const float*)d_in[22];
    const float* W2 = (const float*)d_in[23];
    const float* b2 = (const float*)d_in[24];
    const float* W3 = (const float*)d_in[25];
    const float* b3 = (const float*)d_in[26];

    char* ws = (char*)d_ws;
    size_t off = 0;
    auto alloc = [&](size_t bytes) -> void* {
        void* p = ws + off;
        off = (off + bytes + 255) & ~(size_t)255;
        return p;
    };
    float* Wp      = (float*)alloc((size_t)ROWS * CC * 4);
    float* bp      = (float*)alloc(3 * CC * 4);
    float* u_src   = (float*)alloc(ROWS * 4);
    float* u_dst   = (float*)alloc(ROWS * 4);
    float* c_sd    = (float*)alloc(6 * 4);
    int* slot_node = (int*)alloc(BB * NS * 4);
    float* coefT   = (float*)alloc(BB * NS * 4);
    float* coefA   = (float*)alloc(BB * NS * 4);
    int* a0slot    = (int*)alloc(BB * 4);
    int* cnt2      = (int*)alloc((size_t)BB * NS * EBK * 4);
    int* entry_src = (int*)alloc((size_t)BB * NS * EBK * CAPC * 4);
    float* zbuf4   = (float*)alloc((size_t)BB * NS * NSUB * ZST * 4);
    float* ppool   = (float*)alloc((size_t)BB * NT * 384 * 4);
    int* done      = (int*)alloc(BB * 16 * 4);
    (void)ws_size; (void)in_sizes; (void)n_in; (void)out_size;

    k1<<<dim3(NWB + BB + BB * EBK), dim3(512), 0, stream>>>(
        Wt, Wa, Wpw, bt, ba, bpw, gatW, attS, attD,
        topic_id, author_id, edge_index, tcnt, acnt,
        Wp, bp, u_src, u_dst, c_sd,
        slot_node, coefT, coefA, a0slot, cnt2, entry_src, done);
    k2<<<dim3(BB * NS * NSUB), dim3(256), 0, stream>>>(
        temb, aemb, pemb, slot_node, cnt2, entry_src,
        u_src, u_dst, c_sd, zbuf4);
    k3<<<dim3(BB * NT), dim3(512), 0, stream>>>(
        zbuf4, slot_node, coefT, coefA, a0slot, Wp, bp, gatB,
        W1, b1, W2, b2, W3, b3,
        ppool, done, (float*)d_out);
}